// Round 2
// baseline (1183.694 us; speedup 1.0000x reference)
//
#include <hip/hip_runtime.h>
#include <hip/hip_bf16.h>
#include <cstdint>
#include <cstddef>

typedef __hip_bfloat16 bf16;

#define NSF 128
#define BN_EPS 1e-3f

__device__ inline float ldf(const float* p) { return *p; }
__device__ inline float ldf(const bf16* p)  { return __bfloat162float(*p); }

// ---------------- graph-norm prep ----------------

// zero deg/cnt/fill in one pass (graph-capture-safe; no hipMemsetAsync)
__global__ void zero3_kernel(float* __restrict__ deg, int* __restrict__ cnt,
                             int* __restrict__ fill, int n) {
    int i = blockIdx.x * blockDim.x + threadIdx.x;
    if (i < n) { deg[i] = 0.0f; cnt[i] = 0; fill[i] = 0; }
}

// deg[col] += w ; cnt[col] += 1  for E edges + N self loops
__global__ void count_kernel(const int* __restrict__ ei, const float* __restrict__ ea,
                             float* __restrict__ deg, int* __restrict__ cnt,
                             int E, int n) {
    int idx = blockIdx.x * blockDim.x + threadIdx.x;
    if (idx < E) {
        int c = ei[E + idx];          // edge_index[1][idx]
        atomicAdd(&deg[c], ea[idx]);
        atomicAdd(&cnt[c], 1);
    } else if (idx < E + n) {
        int i = idx - E;              // self loop, weight 1
        atomicAdd(&deg[i], 1.0f);
        atomicAdd(&cnt[i], 1);
    }
}

__global__ void dinv_kernel(const float* __restrict__ deg, float* __restrict__ dinv, int n) {
    int i = blockIdx.x * blockDim.x + threadIdx.x;
    if (i < n) {
        float d = deg[i];
        dinv[i] = (d > 0.0f) ? rsqrtf(d) : 0.0f;
    }
}

// single-block exclusive scan of cnt[0..n) -> row_ptr[0..n]
__global__ void scan_kernel(const int* __restrict__ cnt, int* __restrict__ row_ptr, int n) {
    __shared__ int part[256];
    int tid = threadIdx.x;
    int chunk = (n + 255) / 256;
    int start = tid * chunk;
    int end = min(start + chunk, n);
    int s = 0;
    for (int i = start; i < end; ++i) s += cnt[i];
    part[tid] = s;
    __syncthreads();
    for (int off = 1; off < 256; off <<= 1) {
        int v = (tid >= off) ? part[tid - off] : 0;
        __syncthreads();
        part[tid] += v;
        __syncthreads();
    }
    int run = (tid == 0) ? 0 : part[tid - 1];
    for (int i = start; i < end; ++i) { row_ptr[i] = run; run += cnt[i]; }
    if (tid == 255) row_ptr[n] = part[255];
}

// scatter edges (and self loops) into CSR slots; csr_w = dinv[row]*w*dinv[col]
__global__ void fill_kernel(const int* __restrict__ ei, const float* __restrict__ ea,
                            const float* __restrict__ dinv,
                            const int* __restrict__ row_ptr, int* __restrict__ fill,
                            int* __restrict__ csr_src, float* __restrict__ csr_w,
                            int E, int n) {
    int idx = blockIdx.x * blockDim.x + threadIdx.x;
    if (idx < E) {
        int r = ei[idx];
        int c = ei[E + idx];
        int p = row_ptr[c] + atomicAdd(&fill[c], 1);
        csr_src[p] = r;
        csr_w[p] = dinv[r] * ea[idx] * dinv[c];
    } else if (idx < E + n) {
        int i = idx - E;
        int p = row_ptr[i] + atomicAdd(&fill[i], 1);
        csr_src[p] = i;
        csr_w[p] = dinv[i] * dinv[i];
    }
}

// ---------------- dense compute ----------------

// C[M,Nd](bf16) = A[M,K](TA) @ B[K,Nd](f32); 64x64 tile, BK=16, 256 thr, 4x4/thread
template <typename TA>
__global__ void gemm_kernel(const TA* __restrict__ A, const float* __restrict__ B,
                            bf16* __restrict__ C, int M, int K, int Nd) {
    __shared__ float As[16][64];
    __shared__ float Bs[16][64];
    int m0 = blockIdx.x * 64;
    int n0 = blockIdx.y * 64;
    int tid = threadIdx.x;
    int tx = tid % 16;      // col group (4 cols)
    int ty = tid / 16;      // row group (4 rows)
    float acc[4][4] = {};
    for (int k0 = 0; k0 < K; k0 += 16) {
        #pragma unroll
        for (int it = 0; it < 4; ++it) {
            int l = tid + it * 256;
            int m = l / 16, kk = l % 16;
            int gm = m0 + m;
            As[kk][m] = (gm < M) ? ldf(&A[(size_t)gm * K + k0 + kk]) : 0.0f;
        }
        #pragma unroll
        for (int it = 0; it < 4; ++it) {
            int l = tid + it * 256;
            int kk = l / 64, nn = l % 64;
            Bs[kk][nn] = B[(size_t)(k0 + kk) * Nd + n0 + nn];
        }
        __syncthreads();
        #pragma unroll
        for (int kk = 0; kk < 16; ++kk) {
            float a[4], b[4];
            #pragma unroll
            for (int i = 0; i < 4; ++i) a[i] = As[kk][ty * 4 + i];
            #pragma unroll
            for (int j = 0; j < 4; ++j) b[j] = Bs[kk][tx * 4 + j];
            #pragma unroll
            for (int i = 0; i < 4; ++i)
                #pragma unroll
                for (int j = 0; j < 4; ++j)
                    acc[i][j] += a[i] * b[j];
        }
        __syncthreads();
    }
    #pragma unroll
    for (int i = 0; i < 4; ++i) {
        int gm = m0 + ty * 4 + i;
        if (gm < M) {
            #pragma unroll
            for (int j = 0; j < 4; ++j)
                C[(size_t)gm * Nd + n0 + tx * 4 + j] = __float2bfloat16(acc[i][j]);
        }
    }
}

// one block per node, one thread per feature:
// out[n][f] = sigmoid( BN( sum_j w_j * hw[src_j][f] + bias[f] ) )
__global__ void agg_kernel(const bf16* __restrict__ hw,
                           const int* __restrict__ row_ptr,
                           const int* __restrict__ csr_src, const float* __restrict__ csr_w,
                           const float* __restrict__ bias,
                           const float* __restrict__ g, const float* __restrict__ be,
                           const float* __restrict__ m, const float* __restrict__ v,
                           bf16* __restrict__ out, int dout, int use_bn) {
    int node = blockIdx.x;
    int f = threadIdx.x;
    int s = row_ptr[node], e = row_ptr[node + 1];
    float acc = 0.0f;
    for (int j = s; j < e; ++j) {
        int src = csr_src[j];
        float w = csr_w[j];
        acc += w * __bfloat162float(hw[(size_t)src * dout + f]);
    }
    acc += bias[f];
    if (use_bn) {
        float scale = g[f] * rsqrtf(v[f] + BN_EPS);
        acc = (acc - m[f]) * scale + be[f];
    }
    float sg = 1.0f / (1.0f + __expf(-acc));
    out[(size_t)node * dout + f] = __float2bfloat16(sg);
}

// h^T h partials: block b covers rows [b*250, b*250+250), 8x8 per thread
__global__ void htht_kernel(const bf16* __restrict__ h, float* __restrict__ partial, int n) {
    __shared__ float hs[16][128];
    int b = blockIdx.x;
    int r0 = b * 250;
    int r1 = min(r0 + 250, n);
    int tid = threadIdx.x;
    int tx = tid % 16, ty = tid / 16;
    float acc[8][8] = {};
    for (int k0 = r0; k0 < r1; k0 += 16) {
        int rows = min(16, r1 - k0);
        for (int l = tid; l < 16 * 128; l += 256) {
            int rr = l / 128, cc = l % 128;
            hs[rr][cc] = (rr < rows) ? __bfloat162float(h[(size_t)(k0 + rr) * 128 + cc]) : 0.0f;
        }
        __syncthreads();
        #pragma unroll
        for (int kk = 0; kk < 16; ++kk) {
            float a[8], bb[8];
            #pragma unroll
            for (int i = 0; i < 8; ++i) a[i] = hs[kk][ty * 8 + i];
            #pragma unroll
            for (int j = 0; j < 8; ++j) bb[j] = hs[kk][tx * 8 + j];
            #pragma unroll
            for (int i = 0; i < 8; ++i)
                #pragma unroll
                for (int j = 0; j < 8; ++j)
                    acc[i][j] += a[i] * bb[j];
        }
        __syncthreads();
    }
    float* p = partial + (size_t)b * 16384;
    #pragma unroll
    for (int i = 0; i < 8; ++i)
        #pragma unroll
        for (int j = 0; j < 8; ++j)
            p[(ty * 8 + i) * 128 + (tx * 8 + j)] = acc[i][j];
}

__global__ void reduce_kernel(const float* __restrict__ partial, float* __restrict__ out, int nchunks) {
    int idx = blockIdx.x * blockDim.x + threadIdx.x;   // 16384 total
    float s = 0.0f;
    for (int c = 0; c < nchunks; ++c) s += partial[(size_t)c * 16384 + idx];
    int i = idx / 128, j = idx % 128;
    out[idx] = (i == j) ? 0.0f : s;
}

// ---------------- launch ----------------
extern "C" void kernel_launch(void* const* d_in, const int* in_sizes, int n_in,
                              void* d_out, int out_size, void* d_ws, size_t ws_size,
                              hipStream_t stream) {
    const float* x  = (const float*)d_in[0];
    const int*   ei = (const int*)d_in[1];
    const float* ea = (const float*)d_in[2];
    const float* W[5];  const float* bvec[5];
    for (int l = 0; l < 5; ++l) { W[l] = (const float*)d_in[3 + 2 * l]; bvec[l] = (const float*)d_in[4 + 2 * l]; }
    const float* g[4]; const float* be[4]; const float* mm[4]; const float* vv[4];
    for (int l = 0; l < 4; ++l) {
        g[l]  = (const float*)d_in[13 + 4 * l];
        be[l] = (const float*)d_in[14 + 4 * l];
        mm[l] = (const float*)d_in[15 + 4 * l];
        vv[l] = (const float*)d_in[16 + 4 * l];
    }
    const int n = in_sizes[0] / NSF;        // 20000
    const int E = in_sizes[1] / 2;          // 500000
    const int EN = E + n;
    const int dims[6] = {128, 256, 512, 256, 128, 128};

    // workspace layout (256B aligned); total ~51 MB
    auto align = [](size_t o) { return (o + 255) & ~(size_t)255; };
    size_t off = 0;
    float* deg     = (float*)((char*)d_ws + off); off = align(off + (size_t)n * 4);
    float* dinv    = (float*)((char*)d_ws + off); off = align(off + (size_t)n * 4);
    int*   cnt     = (int*)  ((char*)d_ws + off); off = align(off + (size_t)n * 4);
    int*   fill    = (int*)  ((char*)d_ws + off); off = align(off + (size_t)n * 4);
    int*   row_ptr = (int*)  ((char*)d_ws + off); off = align(off + (size_t)(n + 1) * 4);
    int*   csr_src = (int*)  ((char*)d_ws + off); off = align(off + (size_t)EN * 4);
    float* csr_w   = (float*)((char*)d_ws + off); off = align(off + (size_t)EN * 4);
    bf16*  hwbuf   = (bf16*) ((char*)d_ws + off); off = align(off + (size_t)n * 512 * 2);
    bf16*  hbuf    = (bf16*) ((char*)d_ws + off); off = align(off + (size_t)n * 512 * 2);
    const int KCH = 80;
    float* partial = (float*)((char*)d_ws + off); off = align(off + (size_t)KCH * 16384 * 4);

    // 1) zero deg/cnt/fill (kernel, not memset — graph-capture-safe)
    zero3_kernel<<<(n + 255) / 256, 256, 0, stream>>>(deg, cnt, fill, n);

    // 2) degree + counts
    {
        int blocks = (EN + 255) / 256;
        count_kernel<<<blocks, 256, 0, stream>>>(ei, ea, deg, cnt, E, n);
    }
    // 3) dinv
    dinv_kernel<<<(n + 255) / 256, 256, 0, stream>>>(deg, dinv, n);
    // 4) scan
    scan_kernel<<<1, 256, 0, stream>>>(cnt, row_ptr, n);
    // 5) fill CSR
    {
        int blocks = (EN + 255) / 256;
        fill_kernel<<<blocks, 256, 0, stream>>>(ei, ea, dinv, row_ptr, fill, csr_src, csr_w, E, n);
    }

    // 6) five GCN layers (GEMM -> gather-aggregate + BN + sigmoid)
    for (int l = 0; l < 5; ++l) {
        int din = dims[l], dout = dims[l + 1];
        dim3 ggrid((n + 63) / 64, dout / 64);
        if (l == 0)
            gemm_kernel<float><<<ggrid, 256, 0, stream>>>(x, W[l], hwbuf, n, din, dout);
        else
            gemm_kernel<bf16><<<ggrid, 256, 0, stream>>>(hbuf, W[l], hwbuf, n, din, dout);
        int use_bn = (l < 4) ? 1 : 0;
        agg_kernel<<<n, dout, 0, stream>>>(hwbuf, row_ptr, csr_src, csr_w, bvec[l],
                                           use_bn ? g[l] : bvec[l], use_bn ? be[l] : bvec[l],
                                           use_bn ? mm[l] : bvec[l], use_bn ? vv[l] : bvec[l],
                                           hbuf, dout, use_bn);
    }

    // 7) final h^T h with zeroed diagonal
    htht_kernel<<<KCH, 256, 0, stream>>>(hbuf, partial, n);
    reduce_kernel<<<16384 / 256, 256, 0, stream>>>(partial, (float*)d_out, KCH);
}

// Round 3
// 809.642 us; speedup vs baseline: 1.4620x; 1.4620x over previous
//
#include <hip/hip_runtime.h>
#include <hip/hip_bf16.h>
#include <cstdint>
#include <cstddef>

typedef __hip_bfloat16 bf16;
typedef __attribute__((ext_vector_type(8))) short short8;   // 8 bf16 in 4 VGPRs (MFMA A/B frag)
typedef __attribute__((ext_vector_type(4))) float f32x4;    // MFMA C/D frag

#define NSF 128
#define BN_EPS 1e-3f

// ---------------- graph-norm prep ----------------

__global__ void zero3_kernel(float* __restrict__ deg, int* __restrict__ cnt,
                             int* __restrict__ fill, int n) {
    int i = blockIdx.x * blockDim.x + threadIdx.x;
    if (i < n) { deg[i] = 0.0f; cnt[i] = 0; fill[i] = 0; }
}

__global__ void count_kernel(const int* __restrict__ ei, const float* __restrict__ ea,
                             float* __restrict__ deg, int* __restrict__ cnt,
                             int E, int n) {
    int idx = blockIdx.x * blockDim.x + threadIdx.x;
    if (idx < E) {
        int c = ei[E + idx];
        atomicAdd(&deg[c], ea[idx]);
        atomicAdd(&cnt[c], 1);
    } else if (idx < E + n) {
        int i = idx - E;
        atomicAdd(&deg[i], 1.0f);
        atomicAdd(&cnt[i], 1);
    }
}

__global__ void dinv_kernel(const float* __restrict__ deg, float* __restrict__ dinv, int n) {
    int i = blockIdx.x * blockDim.x + threadIdx.x;
    if (i < n) {
        float d = deg[i];
        dinv[i] = (d > 0.0f) ? rsqrtf(d) : 0.0f;
    }
}

__global__ void scan_kernel(const int* __restrict__ cnt, int* __restrict__ row_ptr, int n) {
    __shared__ int part[256];
    int tid = threadIdx.x;
    int chunk = (n + 255) / 256;
    int start = tid * chunk;
    int end = min(start + chunk, n);
    int s = 0;
    for (int i = start; i < end; ++i) s += cnt[i];
    part[tid] = s;
    __syncthreads();
    for (int off = 1; off < 256; off <<= 1) {
        int v = (tid >= off) ? part[tid - off] : 0;
        __syncthreads();
        part[tid] += v;
        __syncthreads();
    }
    int run = (tid == 0) ? 0 : part[tid - 1];
    for (int i = start; i < end; ++i) { row_ptr[i] = run; run += cnt[i]; }
    if (tid == 255) row_ptr[n] = part[255];
}

__global__ void fill_kernel(const int* __restrict__ ei, const float* __restrict__ ea,
                            const float* __restrict__ dinv,
                            const int* __restrict__ row_ptr, int* __restrict__ fill,
                            int* __restrict__ csr_src, float* __restrict__ csr_w,
                            int E, int n) {
    int idx = blockIdx.x * blockDim.x + threadIdx.x;
    if (idx < E) {
        int r = ei[idx];
        int c = ei[E + idx];
        int p = row_ptr[c] + atomicAdd(&fill[c], 1);
        csr_src[p] = r;
        csr_w[p] = dinv[r] * ea[idx] * dinv[c];
    } else if (idx < E + n) {
        int i = idx - E;
        int p = row_ptr[i] + atomicAdd(&fill[i], 1);
        csr_src[p] = i;
        csr_w[p] = dinv[i] * dinv[i];
    }
}

// ---------------- dtype prep ----------------

__global__ void cvt_kernel(const float* __restrict__ x, bf16* __restrict__ y, int count) {
    int i = blockIdx.x * blockDim.x + threadIdx.x;
    if (i < count) y[i] = __float2bfloat16(x[i]);
}

// Wt[n*K + k] = bf16(W[k*N + n])
__global__ void wt_kernel(const float* __restrict__ W, bf16* __restrict__ Wt, int K, int N) {
    int idx = blockIdx.x * blockDim.x + threadIdx.x;
    if (idx < K * N) {
        int nn = idx / K, kk = idx % K;
        Wt[idx] = __float2bfloat16(W[(size_t)kk * N + nn]);
    }
}

// ---------------- MFMA GEMM: C[M,N] = A[M,K] @ Wt[N,K]^T (all bf16, fp32 acc) ----------------
// BM=64, BN=128, BK=32, 256 threads (4 waves). Wave w owns rows [w*16,w*16+16).
#define GPAD 8  // +8 bf16 (=16B) row pad: keeps 16B alignment, breaks pow2 bank stride

__global__ __launch_bounds__(256) void mfma_gemm_kernel(
    const bf16* __restrict__ A, const bf16* __restrict__ Wt,
    bf16* __restrict__ C, int M, int K, int N) {
    __shared__ bf16 As[64][32 + GPAD];
    __shared__ bf16 Bs[128][32 + GPAD];
    int m0 = blockIdx.x * 64;
    int n0 = blockIdx.y * 128;
    int tid = threadIdx.x;
    int wave = tid >> 6, lane = tid & 63;
    int lrow = lane & 15, quad = lane >> 4;

    f32x4 acc[8] = {};

    int r = tid >> 2;      // 0..63
    int seg = tid & 3;     // 0..3  (8 bf16 = 16B per seg)

    for (int k0 = 0; k0 < K; k0 += 32) {
        // stage A tile 64x32
        uint4 av; av.x = av.y = av.z = av.w = 0u;
        int gm = m0 + r;
        if (gm < M) av = *(const uint4*)(A + (size_t)gm * K + k0 + seg * 8);
        *(uint4*)(&As[r][seg * 8]) = av;
        // stage Wt tile 128x32 (2 rows/thread); N,K always multiples -> no guard
        *(uint4*)(&Bs[r][seg * 8]) =
            *(const uint4*)(Wt + (size_t)(n0 + r) * K + k0 + seg * 8);
        *(uint4*)(&Bs[r + 64][seg * 8]) =
            *(const uint4*)(Wt + (size_t)(n0 + r + 64) * K + k0 + seg * 8);
        __syncthreads();

        // A frag: lane holds A[m=lrow][k=quad*8+j]
        short8 afrag = *(const short8*)(&As[wave * 16 + lrow][quad * 8]);
        #pragma unroll
        for (int t = 0; t < 8; ++t) {
            // B frag: lane holds B[k=quad*8+j][n=lrow] = Wt[n][k]
            short8 bfrag = *(const short8*)(&Bs[t * 16 + lrow][quad * 8]);
            acc[t] = __builtin_amdgcn_mfma_f32_16x16x32_bf16(afrag, bfrag, acc[t], 0, 0, 0);
        }
        __syncthreads();
    }
    // C/D layout: col = lane&15, row = quad*4 + reg
    #pragma unroll
    for (int t = 0; t < 8; ++t) {
        #pragma unroll
        for (int rr = 0; rr < 4; ++rr) {
            int gm = m0 + wave * 16 + quad * 4 + rr;
            int gn = n0 + t * 16 + lrow;
            if (gm < M) C[(size_t)gm * N + gn] = __float2bfloat16(acc[t][rr]);
        }
    }
}

// ---------------- vectorized aggregation ----------------

__device__ inline float bfu(unsigned int u16) {
    union { unsigned int u; float f; } c; c.u = u16 << 16; return c.f;
}
__device__ inline void fma_unpack(unsigned int q, float w, float* acc) {
    acc[0] += w * bfu(q & 0xffffu);
    acc[1] += w * bfu(q >> 16);
}
__device__ inline void fma_unpack(uint2 q, float w, float* acc) {
    fma_unpack(q.x, w, acc); fma_unpack(q.y, w, acc + 2);
}
__device__ inline void fma_unpack(uint4 q, float w, float* acc) {
    fma_unpack(q.x, w, acc);     fma_unpack(q.y, w, acc + 2);
    fma_unpack(q.z, w, acc + 4); fma_unpack(q.w, w, acc + 6);
}

template <int VEC> struct UVec;
template <> struct UVec<2> { typedef unsigned int T; };
template <> struct UVec<4> { typedef uint2 T; };
template <> struct UVec<8> { typedef uint4 T; };

// wave per node; lane owns VEC consecutive features (dout = 64*VEC)
template <int VEC>
__global__ __launch_bounds__(256) void agg_vec_kernel(
    const bf16* __restrict__ hw,
    const int* __restrict__ row_ptr,
    const int* __restrict__ csr_src, const float* __restrict__ csr_w,
    const float* __restrict__ bias,
    const float* __restrict__ g, const float* __restrict__ be,
    const float* __restrict__ m, const float* __restrict__ v,
    bf16* __restrict__ out, int n, int use_bn) {
    typedef typename UVec<VEC>::T T;
    const int dout = VEC * 64;
    int wave = threadIdx.x >> 6;
    int lane = threadIdx.x & 63;
    int node = blockIdx.x * 4 + wave;
    if (node >= n) return;
    int s = row_ptr[node], e = row_ptr[node + 1];
    float acc[VEC];
    #pragma unroll
    for (int i = 0; i < VEC; ++i) acc[i] = 0.0f;
    const size_t base = (size_t)lane * VEC;

    int j = s;
    for (; j + 1 < e; j += 2) {
        int s0 = csr_src[j], s1 = csr_src[j + 1];
        float w0 = csr_w[j], w1 = csr_w[j + 1];
        T q0 = *(const T*)(hw + (size_t)s0 * dout + base);
        T q1 = *(const T*)(hw + (size_t)s1 * dout + base);
        fma_unpack(q0, w0, acc);
        fma_unpack(q1, w1, acc);
    }
    if (j < e) {
        int s0 = csr_src[j];
        float w0 = csr_w[j];
        T q0 = *(const T*)(hw + (size_t)s0 * dout + base);
        fma_unpack(q0, w0, acc);
    }

    #pragma unroll
    for (int i = 0; i < VEC; ++i) {
        int f = (int)base + i;
        float a = acc[i] + bias[f];
        if (use_bn) {
            float scale = g[f] * rsqrtf(v[f] + BN_EPS);
            a = (a - m[f]) * scale + be[f];
        }
        float sg = 1.0f / (1.0f + __expf(-a));
        out[(size_t)node * dout + f] = __float2bfloat16(sg);
    }
}

// ---------------- final h^T h ----------------

__global__ void htht_kernel(const bf16* __restrict__ h, float* __restrict__ partial, int n) {
    __shared__ float hs[16][128];
    int b = blockIdx.x;
    int r0 = b * 250;
    int r1 = min(r0 + 250, n);
    int tid = threadIdx.x;
    int tx = tid % 16, ty = tid / 16;
    float acc[8][8] = {};
    for (int k0 = r0; k0 < r1; k0 += 16) {
        int rows = min(16, r1 - k0);
        for (int l = tid; l < 16 * 128; l += 256) {
            int rr = l / 128, cc = l % 128;
            hs[rr][cc] = (rr < rows) ? __bfloat162float(h[(size_t)(k0 + rr) * 128 + cc]) : 0.0f;
        }
        __syncthreads();
        #pragma unroll
        for (int kk = 0; kk < 16; ++kk) {
            float a[8], bb[8];
            #pragma unroll
            for (int i = 0; i < 8; ++i) a[i] = hs[kk][ty * 8 + i];
            #pragma unroll
            for (int j = 0; j < 8; ++j) bb[j] = hs[kk][tx * 8 + j];
            #pragma unroll
            for (int i = 0; i < 8; ++i)
                #pragma unroll
                for (int j = 0; j < 8; ++j)
                    acc[i][j] += a[i] * bb[j];
        }
        __syncthreads();
    }
    float* p = partial + (size_t)b * 16384;
    #pragma unroll
    for (int i = 0; i < 8; ++i)
        #pragma unroll
        for (int j = 0; j < 8; ++j)
            p[(ty * 8 + i) * 128 + (tx * 8 + j)] = acc[i][j];
}

__global__ void reduce_kernel(const float* __restrict__ partial, float* __restrict__ out, int nchunks) {
    int idx = blockIdx.x * blockDim.x + threadIdx.x;   // 16384 total
    float s = 0.0f;
    for (int c = 0; c < nchunks; ++c) s += partial[(size_t)c * 16384 + idx];
    int i = idx / 128, j = idx % 128;
    out[idx] = (i == j) ? 0.0f : s;
}

// ---------------- launch ----------------
extern "C" void kernel_launch(void* const* d_in, const int* in_sizes, int n_in,
                              void* d_out, int out_size, void* d_ws, size_t ws_size,
                              hipStream_t stream) {
    const float* x  = (const float*)d_in[0];
    const int*   ei = (const int*)d_in[1];
    const float* ea = (const float*)d_in[2];
    const float* W[5];  const float* bvec[5];
    for (int l = 0; l < 5; ++l) { W[l] = (const float*)d_in[3 + 2 * l]; bvec[l] = (const float*)d_in[4 + 2 * l]; }
    const float* g[4]; const float* be[4]; const float* mm[4]; const float* vv[4];
    for (int l = 0; l < 4; ++l) {
        g[l]  = (const float*)d_in[13 + 4 * l];
        be[l] = (const float*)d_in[14 + 4 * l];
        mm[l] = (const float*)d_in[15 + 4 * l];
        vv[l] = (const float*)d_in[16 + 4 * l];
    }
    const int n = in_sizes[0] / NSF;        // 20000
    const int E = in_sizes[1] / 2;          // 500000
    const int EN = E + n;
    const int dims[6] = {128, 256, 512, 256, 128, 128};
    const int wtoff[5] = {0, 32768, 163840, 294912, 327680};   // cumulative K*N
    const int wtelems = 344064;

    // workspace layout (256B aligned); total ~51.5 MB
    auto align = [](size_t o) { return (o + 255) & ~(size_t)255; };
    size_t off = 0;
    float* deg     = (float*)((char*)d_ws + off); off = align(off + (size_t)n * 4);
    float* dinv    = (float*)((char*)d_ws + off); off = align(off + (size_t)n * 4);
    int*   cnt     = (int*)  ((char*)d_ws + off); off = align(off + (size_t)n * 4);
    int*   fill    = (int*)  ((char*)d_ws + off); off = align(off + (size_t)n * 4);
    int*   row_ptr = (int*)  ((char*)d_ws + off); off = align(off + (size_t)(n + 1) * 4);
    int*   csr_src = (int*)  ((char*)d_ws + off); off = align(off + (size_t)EN * 4);
    float* csr_w   = (float*)((char*)d_ws + off); off = align(off + (size_t)EN * 4);
    bf16*  wtbuf   = (bf16*) ((char*)d_ws + off); off = align(off + (size_t)wtelems * 2);
    bf16*  hwbuf   = (bf16*) ((char*)d_ws + off); off = align(off + (size_t)n * 512 * 2);
    bf16*  hbuf    = (bf16*) ((char*)d_ws + off); off = align(off + (size_t)n * 512 * 2);
    const int KCH = 80;
    float* partial = (float*)((char*)d_ws + off); off = align(off + (size_t)KCH * 16384 * 4);

    // graph prep
    zero3_kernel<<<(n + 255) / 256, 256, 0, stream>>>(deg, cnt, fill, n);
    count_kernel<<<(EN + 255) / 256, 256, 0, stream>>>(ei, ea, deg, cnt, E, n);
    dinv_kernel<<<(n + 255) / 256, 256, 0, stream>>>(deg, dinv, n);
    scan_kernel<<<1, 256, 0, stream>>>(cnt, row_ptr, n);
    fill_kernel<<<(EN + 255) / 256, 256, 0, stream>>>(ei, ea, dinv, row_ptr, fill, csr_src, csr_w, E, n);

    // dtype prep: x -> bf16 (into hbuf, consumed by layer-0 GEMM before agg overwrites);
    // W -> Wt bf16
    cvt_kernel<<<(n * 128 + 255) / 256, 256, 0, stream>>>(x, hbuf, n * 128);
    for (int l = 0; l < 5; ++l) {
        int K = dims[l], N = dims[l + 1];
        wt_kernel<<<(K * N + 255) / 256, 256, 0, stream>>>(W[l], wtbuf + wtoff[l], K, N);
    }

    // five GCN layers
    for (int l = 0; l < 5; ++l) {
        int K = dims[l], N = dims[l + 1];
        dim3 ggrid((n + 63) / 64, N / 128);
        mfma_gemm_kernel<<<ggrid, 256, 0, stream>>>(hbuf, wtbuf + wtoff[l], hwbuf, n, K, N);
        int use_bn = (l < 4) ? 1 : 0;
        const float* gg = use_bn ? g[l] : bvec[l];
        const float* bb = use_bn ? be[l] : bvec[l];
        const float* mmv = use_bn ? mm[l] : bvec[l];
        const float* vvv = use_bn ? vv[l] : bvec[l];
        int blocks = (n + 3) / 4;
        if (N == 512)
            agg_vec_kernel<8><<<blocks, 256, 0, stream>>>(hwbuf, row_ptr, csr_src, csr_w,
                                                          bvec[l], gg, bb, mmv, vvv, hbuf, n, use_bn);
        else if (N == 256)
            agg_vec_kernel<4><<<blocks, 256, 0, stream>>>(hwbuf, row_ptr, csr_src, csr_w,
                                                          bvec[l], gg, bb, mmv, vvv, hbuf, n, use_bn);
        else
            agg_vec_kernel<2><<<blocks, 256, 0, stream>>>(hwbuf, row_ptr, csr_src, csr_w,
                                                          bvec[l], gg, bb, mmv, vvv, hbuf, n, use_bn);
    }

    // final h^T h with zeroed diagonal
    htht_kernel<<<KCH, 256, 0, stream>>>(hbuf, partial, n);
    reduce_kernel<<<16384 / 256, 256, 0, stream>>>(partial, (float*)d_out, KCH);
}

// Round 5
// 536.673 us; speedup vs baseline: 2.2056x; 1.5086x over previous
//
#include <hip/hip_runtime.h>
#include <hip/hip_bf16.h>
#include <cstdint>
#include <cstddef>

typedef __hip_bfloat16 bf16;
typedef __attribute__((ext_vector_type(8))) short short8;   // 8 bf16 (MFMA A/B frag)
typedef __attribute__((ext_vector_type(4))) float f32x4;    // MFMA C/D frag

#define NSF 128
#define BN_EPS 1e-3f

// ---------------- graph-norm prep ----------------

__global__ void zero3_kernel(float* __restrict__ deg, int* __restrict__ cnt,
                             int* __restrict__ fill, int n) {
    int i = blockIdx.x * blockDim.x + threadIdx.x;
    if (i < n) { deg[i] = 0.0f; cnt[i] = 0; fill[i] = 0; }
}

__global__ void count_kernel(const int* __restrict__ ei, const float* __restrict__ ea,
                             float* __restrict__ deg, int* __restrict__ cnt,
                             int E, int n) {
    int idx = blockIdx.x * blockDim.x + threadIdx.x;
    if (idx < E) {
        int c = ei[E + idx];
        atomicAdd(&deg[c], ea[idx]);
        atomicAdd(&cnt[c], 1);
    } else if (idx < E + n) {
        int i = idx - E;
        atomicAdd(&deg[i], 1.0f);
        atomicAdd(&cnt[i], 1);
    }
}

__global__ void dinv_kernel(const float* __restrict__ deg, float* __restrict__ dinv, int n) {
    int i = blockIdx.x * blockDim.x + threadIdx.x;
    if (i < n) {
        float d = deg[i];
        dinv[i] = (d > 0.0f) ? rsqrtf(d) : 0.0f;
    }
}

__global__ void scan_kernel(const int* __restrict__ cnt, int* __restrict__ row_ptr, int n) {
    __shared__ int part[256];
    int tid = threadIdx.x;
    int chunk = (n + 255) / 256;
    int start = tid * chunk;
    int end = min(start + chunk, n);
    int s = 0;
    for (int i = start; i < end; ++i) s += cnt[i];
    part[tid] = s;
    __syncthreads();
    for (int off = 1; off < 256; off <<= 1) {
        int v = (tid >= off) ? part[tid - off] : 0;
        __syncthreads();
        part[tid] += v;
        __syncthreads();
    }
    int run = (tid == 0) ? 0 : part[tid - 1];
    for (int i = start; i < end; ++i) { row_ptr[i] = run; run += cnt[i]; }
    if (tid == 255) row_ptr[n] = part[255];
}

__global__ void fill_kernel(const int* __restrict__ ei, const float* __restrict__ ea,
                            const float* __restrict__ dinv,
                            const int* __restrict__ row_ptr, int* __restrict__ fill,
                            int* __restrict__ csr_src, float* __restrict__ csr_w,
                            int E, int n) {
    int idx = blockIdx.x * blockDim.x + threadIdx.x;
    if (idx < E) {
        int r = ei[idx];
        int c = ei[E + idx];
        int p = row_ptr[c] + atomicAdd(&fill[c], 1);
        csr_src[p] = r;
        csr_w[p] = dinv[r] * ea[idx] * dinv[c];
    } else if (idx < E + n) {
        int i = idx - E;
        int p = row_ptr[i] + atomicAdd(&fill[i], 1);
        csr_src[p] = i;
        csr_w[p] = dinv[i] * dinv[i];
    }
}

// ---------------- dtype prep ----------------

__global__ void cvt_kernel(const float* __restrict__ x, bf16* __restrict__ y, int count) {
    int i = blockIdx.x * blockDim.x + threadIdx.x;
    if (i < count) y[i] = __float2bfloat16(x[i]);
}

// Wt[n*K + k] = bf16(W[k*N + n])
__global__ void wt_kernel(const float* __restrict__ W, bf16* __restrict__ Wt, int K, int N) {
    int idx = blockIdx.x * blockDim.x + threadIdx.x;
    if (idx < K * N) {
        int nn = idx / K, kk = idx % K;
        Wt[idx] = __float2bfloat16(W[(size_t)kk * N + nn]);
    }
}

// ---------------- MFMA GEMM: C[M,N] = A[M,K] @ Wt[N,K]^T, fused epilogue ----------------
// mode 0: raw store; mode 1: sigmoid(BN(acc+bias)); (agg-last layers use mode 0)
#define GPAD 8

__global__ __launch_bounds__(256) void mfma_gemm_kernel(
    const bf16* __restrict__ A, const bf16* __restrict__ Wt,
    bf16* __restrict__ C, int M, int K, int N, int mode,
    const float* __restrict__ bias, const float* __restrict__ g,
    const float* __restrict__ be, const float* __restrict__ m,
    const float* __restrict__ v) {
    __shared__ bf16 As[64][32 + GPAD];
    __shared__ bf16 Bs[128][32 + GPAD];
    int m0 = blockIdx.x * 64;
    int n0 = blockIdx.y * 128;
    int tid = threadIdx.x;
    int wave = tid >> 6, lane = tid & 63;
    int lrow = lane & 15, quad = lane >> 4;

    f32x4 acc[8] = {};

    int r = tid >> 2;      // 0..63
    int seg = tid & 3;     // 0..3

    for (int k0 = 0; k0 < K; k0 += 32) {
        uint4 av; av.x = av.y = av.z = av.w = 0u;
        int gm = m0 + r;
        if (gm < M) av = *(const uint4*)(A + (size_t)gm * K + k0 + seg * 8);
        *(uint4*)(&As[r][seg * 8]) = av;
        *(uint4*)(&Bs[r][seg * 8]) =
            *(const uint4*)(Wt + (size_t)(n0 + r) * K + k0 + seg * 8);
        *(uint4*)(&Bs[r + 64][seg * 8]) =
            *(const uint4*)(Wt + (size_t)(n0 + r + 64) * K + k0 + seg * 8);
        __syncthreads();

        short8 afrag = *(const short8*)(&As[wave * 16 + lrow][quad * 8]);
        #pragma unroll
        for (int t = 0; t < 8; ++t) {
            short8 bfrag = *(const short8*)(&Bs[t * 16 + lrow][quad * 8]);
            acc[t] = __builtin_amdgcn_mfma_f32_16x16x32_bf16(afrag, bfrag, acc[t], 0, 0, 0);
        }
        __syncthreads();
    }
    // C/D: col = lane&15, row = quad*4 + reg
    #pragma unroll
    for (int t = 0; t < 8; ++t) {
        int gn = n0 + t * 16 + lrow;
        float bsc = 0.0f, scale = 1.0f, mean = 0.0f, beta = 0.0f;
        if (mode == 1) {
            bsc = bias[gn];
            scale = g[gn] * rsqrtf(v[gn] + BN_EPS);
            mean = m[gn];
            beta = be[gn];
        }
        #pragma unroll
        for (int rr = 0; rr < 4; ++rr) {
            int gm = m0 + wave * 16 + quad * 4 + rr;
            if (gm < M) {
                float a = acc[t][rr];
                if (mode == 1) {
                    a = (a + bsc - mean) * scale + beta;
                    a = 1.0f / (1.0f + __expf(-a));
                }
                C[(size_t)gm * N + gn] = __float2bfloat16(a);
            }
        }
    }
}

// ---------------- vectorized aggregation ----------------

__device__ inline float bfu(unsigned int u16) {
    union { unsigned int u; float f; } c; c.u = u16 << 16; return c.f;
}
__device__ inline void fma_unpack(unsigned int q, float w, float* acc) {
    acc[0] += w * bfu(q & 0xffffu);
    acc[1] += w * bfu(q >> 16);
}
__device__ inline void fma_unpack(uint2 q, float w, float* acc) {
    fma_unpack(q.x, w, acc); fma_unpack(q.y, w, acc + 2);
}
__device__ inline void fma_unpack(uint4 q, float w, float* acc) {
    fma_unpack(q.x, w, acc);     fma_unpack(q.y, w, acc + 2);
    fma_unpack(q.z, w, acc + 4); fma_unpack(q.w, w, acc + 6);
}

template <int VEC> struct UVec;
template <> struct UVec<2> { typedef unsigned int T; };
template <> struct UVec<4> { typedef uint2 T; };
template <> struct UVec<8> { typedef uint4 T; };

// wave per node; lane owns VEC consecutive features (dfeat = 64*VEC)
// mode 0: plain weighted sum (agg-first); 1: bias+BN+sigmoid; 2: bias+sigmoid
template <int VEC>
__global__ __launch_bounds__(256) void agg_vec_kernel(
    const bf16* __restrict__ hw,
    const int* __restrict__ row_ptr,
    const int* __restrict__ csr_src, const float* __restrict__ csr_w,
    const float* __restrict__ bias,
    const float* __restrict__ g, const float* __restrict__ be,
    const float* __restrict__ m, const float* __restrict__ v,
    bf16* __restrict__ out, int n, int mode) {
    typedef typename UVec<VEC>::T T;
    const int dfeat = VEC * 64;
    int wave = threadIdx.x >> 6;
    int lane = threadIdx.x & 63;
    int node = blockIdx.x * 4 + wave;
    if (node >= n) return;
    int s = row_ptr[node], e = row_ptr[node + 1];
    float acc[VEC];
    #pragma unroll
    for (int i = 0; i < VEC; ++i) acc[i] = 0.0f;
    const size_t base = (size_t)lane * VEC;

    int j = s;
    for (; j + 3 < e; j += 4) {
        int s0 = csr_src[j],     s1 = csr_src[j + 1];
        int s2 = csr_src[j + 2], s3 = csr_src[j + 3];
        float w0 = csr_w[j],     w1 = csr_w[j + 1];
        float w2 = csr_w[j + 2], w3 = csr_w[j + 3];
        T q0 = *(const T*)(hw + (size_t)s0 * dfeat + base);
        T q1 = *(const T*)(hw + (size_t)s1 * dfeat + base);
        T q2 = *(const T*)(hw + (size_t)s2 * dfeat + base);
        T q3 = *(const T*)(hw + (size_t)s3 * dfeat + base);
        fma_unpack(q0, w0, acc);
        fma_unpack(q1, w1, acc);
        fma_unpack(q2, w2, acc);
        fma_unpack(q3, w3, acc);
    }
    for (; j < e; ++j) {
        int s0 = csr_src[j];
        float w0 = csr_w[j];
        T q0 = *(const T*)(hw + (size_t)s0 * dfeat + base);
        fma_unpack(q0, w0, acc);
    }

    #pragma unroll
    for (int i = 0; i < VEC; ++i) {
        int f = (int)base + i;
        float a = acc[i];
        if (mode != 0) {
            a += bias[f];
            if (mode == 1) {
                float scale = g[f] * rsqrtf(v[f] + BN_EPS);
                a = (a - m[f]) * scale + be[f];
            }
            a = 1.0f / (1.0f + __expf(-a));
        }
        out[(size_t)node * dfeat + f] = __float2bfloat16(a);
    }
}

// ---------------- final h^T h via MFMA ----------------
// block b covers k-rows [b*256, b*256+256): 8 k-tiles of 32.
// LDS staged transposed: hsT[f][kk] so A/B frags are contiguous ds_read_b128.
#define TPAD 8   // row stride 40 bf16 = 80 B (16B aligned)

__global__ __launch_bounds__(256) void htht_mfma_kernel(
    const bf16* __restrict__ h, float* __restrict__ partial, int n) {
    __shared__ bf16 hsT[128][32 + TPAD];
    int b = blockIdx.x;
    int tid = threadIdx.x;
    int wave = tid >> 6, lane = tid & 63;
    int lrow = lane & 15, quad = lane >> 4;

    f32x4 acc[2][8] = {};

    int kk = tid >> 3;       // 0..31
    int seg = tid & 7;       // 0..7

    for (int kt = 0; kt < 8; ++kt) {
        int k0 = b * 256 + kt * 32;
        #pragma unroll
        for (int s2 = 0; s2 < 2; ++s2) {
            int fs = (seg + s2 * 8) * 8;       // feature start
            int gk = k0 + kk;
            uint4 q; q.x = q.y = q.z = q.w = 0u;
            if (gk < n) q = *(const uint4*)(h + (size_t)gk * 128 + fs);
            const unsigned short* u = (const unsigned short*)&q;
            #pragma unroll
            for (int i = 0; i < 8; ++i)
                *((unsigned short*)&hsT[fs + i][kk]) = u[i];
        }
        __syncthreads();
        // wave w computes C rows [w*32, w*32+32)
        short8 af0 = *(const short8*)(&hsT[wave * 32 + lrow][quad * 8]);
        short8 af1 = *(const short8*)(&hsT[wave * 32 + 16 + lrow][quad * 8]);
        #pragma unroll
        for (int t = 0; t < 8; ++t) {
            short8 bfrag = *(const short8*)(&hsT[t * 16 + lrow][quad * 8]);
            acc[0][t] = __builtin_amdgcn_mfma_f32_16x16x32_bf16(af0, bfrag, acc[0][t], 0, 0, 0);
            acc[1][t] = __builtin_amdgcn_mfma_f32_16x16x32_bf16(af1, bfrag, acc[1][t], 0, 0, 0);
        }
        __syncthreads();
    }
    float* p = partial + (size_t)b * 16384;
    #pragma unroll
    for (int a_ = 0; a_ < 2; ++a_) {
        #pragma unroll
        for (int t = 0; t < 8; ++t) {
            #pragma unroll
            for (int rr = 0; rr < 4; ++rr) {
                int gm = wave * 32 + a_ * 16 + quad * 4 + rr;
                int gn = t * 16 + lrow;
                p[gm * 128 + gn] = acc[a_][t][rr];
            }
        }
    }
}

__global__ void reduce_kernel(const float* __restrict__ partial, float* __restrict__ out, int nchunks) {
    int idx = blockIdx.x * blockDim.x + threadIdx.x;   // 16384 total
    float s = 0.0f;
    for (int c = 0; c < nchunks; ++c) s += partial[(size_t)c * 16384 + idx];
    int i = idx / 128, j = idx % 128;
    out[idx] = (i == j) ? 0.0f : s;
}

// ---------------- launch ----------------
extern "C" void kernel_launch(void* const* d_in, const int* in_sizes, int n_in,
                              void* d_out, int out_size, void* d_ws, size_t ws_size,
                              hipStream_t stream) {
    const float* x  = (const float*)d_in[0];
    const int*   ei = (const int*)d_in[1];
    const float* ea = (const float*)d_in[2];
    const float* W[5];  const float* bvec[5];
    for (int l = 0; l < 5; ++l) { W[l] = (const float*)d_in[3 + 2 * l]; bvec[l] = (const float*)d_in[4 + 2 * l]; }
    const float* g[4]; const float* be[4]; const float* mm[4]; const float* vv[4];
    for (int l = 0; l < 4; ++l) {
        g[l]  = (const float*)d_in[13 + 4 * l];
        be[l] = (const float*)d_in[14 + 4 * l];
        mm[l] = (const float*)d_in[15 + 4 * l];
        vv[l] = (const float*)d_in[16 + 4 * l];
    }
    const int n = in_sizes[0] / NSF;        // 20000
    const int E = in_sizes[1] / 2;          // 500000
    const int EN = E + n;
    const int dims[6] = {128, 256, 512, 256, 128, 128};
    const int wtoff[5] = {0, 32768, 163840, 294912, 327680};
    const int wtelems = 344064;

    // workspace layout (256B aligned); ~67 MB
    auto align = [](size_t o) { return (o + 255) & ~(size_t)255; };
    size_t off = 0;
    float* deg     = (float*)((char*)d_ws + off); off = align(off + (size_t)n * 4);
    float* dinv    = (float*)((char*)d_ws + off); off = align(off + (size_t)n * 4);
    int*   cnt     = (int*)  ((char*)d_ws + off); off = align(off + (size_t)n * 4);
    int*   fill    = (int*)  ((char*)d_ws + off); off = align(off + (size_t)n * 4);
    int*   row_ptr = (int*)  ((char*)d_ws + off); off = align(off + (size_t)(n + 1) * 4);
    int*   csr_src = (int*)  ((char*)d_ws + off); off = align(off + (size_t)EN * 4);
    float* csr_w   = (float*)((char*)d_ws + off); off = align(off + (size_t)EN * 4);
    bf16*  wtbuf   = (bf16*) ((char*)d_ws + off); off = align(off + (size_t)wtelems * 2);
    bf16*  hbuf    = (bf16*) ((char*)d_ws + off); off = align(off + (size_t)n * 512 * 2);
    bf16*  abuf    = (bf16*) ((char*)d_ws + off); off = align(off + (size_t)n * 512 * 2);
    const int KCH = (20000 + 255) / 256;    // 79
    float* partial = (float*)((char*)d_ws + off); off = align(off + (size_t)KCH * 16384 * 4);

    // graph prep
    zero3_kernel<<<(n + 255) / 256, 256, 0, stream>>>(deg, cnt, fill, n);
    count_kernel<<<(EN + 255) / 256, 256, 0, stream>>>(ei, ea, deg, cnt, E, n);
    dinv_kernel<<<(n + 255) / 256, 256, 0, stream>>>(deg, dinv, n);
    scan_kernel<<<1, 256, 0, stream>>>(cnt, row_ptr, n);
    fill_kernel<<<(EN + 255) / 256, 256, 0, stream>>>(ei, ea, dinv, row_ptr, fill, csr_src, csr_w, E, n);

    // dtype prep
    cvt_kernel<<<(n * 128 + 255) / 256, 256, 0, stream>>>(x, hbuf, n * 128);
    for (int l = 0; l < 5; ++l) {
        int K = dims[l], N = dims[l + 1];
        wt_kernel<<<(K * N + 255) / 256, 256, 0, stream>>>(W[l], wtbuf + wtoff[l], K, N);
    }

    int ablocks = (n + 3) / 4;
    auto gemm = [&](const bf16* A, int l, bf16* C, int mode) {
        int K = dims[l], N = dims[l + 1];
        dim3 gg((n + 63) / 64, N / 128);
        int bi = (l < 4) ? l : 0;  // BN params only used when mode==1 (l<2)
        mfma_gemm_kernel<<<gg, 256, 0, stream>>>(A, wtbuf + wtoff[l], C, n, K, N, mode,
                                                 bvec[l], g[bi], be[bi], mm[bi], vv[bi]);
    };

    // L1 (128->256): agg-first in 128-dim, GEMM fused bias+BN+sigmoid
    agg_vec_kernel<2><<<ablocks, 256, 0, stream>>>(hbuf, row_ptr, csr_src, csr_w,
        bvec[0], bvec[0], bvec[0], bvec[0], bvec[0], abuf, n, 0);
    gemm(abuf, 0, hbuf, 1);
    // L2 (256->512): agg-first in 256-dim
    agg_vec_kernel<4><<<ablocks, 256, 0, stream>>>(hbuf, row_ptr, csr_src, csr_w,
        bvec[1], bvec[1], bvec[1], bvec[1], bvec[1], abuf, n, 0);
    gemm(abuf, 1, hbuf, 1);
    // L3 (512->256): GEMM raw, agg-last in 256-dim with bias+BN+sigmoid
    gemm(hbuf, 2, abuf, 0);
    agg_vec_kernel<4><<<ablocks, 256, 0, stream>>>(abuf, row_ptr, csr_src, csr_w,
        bvec[2], g[2], be[2], mm[2], vv[2], hbuf, n, 1);
    // L4 (256->128): GEMM raw, agg-last with bias+BN+sigmoid
    gemm(hbuf, 3, abuf, 0);
    agg_vec_kernel<2><<<ablocks, 256, 0, stream>>>(abuf, row_ptr, csr_src, csr_w,
        bvec[3], g[3], be[3], mm[3], vv[3], hbuf, n, 1);
    // L5 (128->128): GEMM raw, agg-last with bias+sigmoid (no BN)
    gemm(hbuf, 4, abuf, 0);
    agg_vec_kernel<2><<<ablocks, 256, 0, stream>>>(abuf, row_ptr, csr_src, csr_w,
        bvec[4], bvec[4], bvec[4], bvec[4], bvec[4], hbuf, n, 2);

    // final h^T h with zeroed diagonal (MFMA)
    htht_mfma_kernel<<<KCH, 256, 0, stream>>>(hbuf, partial, n);
    reduce_kernel<<<16384 / 256, 256, 0, stream>>>(partial, (float*)d_out, KCH);
}